// Round 10
// baseline (2805.750 us; speedup 1.0000x reference)
//
#include <hip/hip_runtime.h>
#include <hip/hip_bf16.h>

#define BATCH 1024
#define HID   512
#define OUTW  348
#define NBH   (BATCH * HID)   // elements per [1024][512] buffer
#define NWL   (2048 * 512)    // per-layer elements per weight matrix

using short8 = __attribute__((ext_vector_type(8))) short;
using bf16x8 = __attribute__((ext_vector_type(8))) __bf16;
using f32x4  = __attribute__((ext_vector_type(4))) float;

__device__ __forceinline__ float bf2f(unsigned short u) {
  union { unsigned int i; float f; } x; x.i = ((unsigned int)u) << 16; return x.f;
}
__device__ __forceinline__ unsigned short f2bf(float f) {
  __hip_bfloat16 b = __float2bfloat16(f);
  return __builtin_bit_cast(unsigned short, b);
}
__device__ __forceinline__ float sigm(float x) { return 1.0f / (1.0f + __expf(-x)); }

__device__ __forceinline__ f32x4 mfma_bf16(short8 a, short8 b, f32x4 c) {
  return __builtin_amdgcn_mfma_f32_16x16x32_bf16(
      __builtin_bit_cast(bf16x8, a), __builtin_bit_cast(bf16x8, b), c, 0, 0, 0);
}

// device-coherent (write-through past L2) stores: sc0 sc1
__device__ __forceinline__ void st128_cc(void* dst, short8 v) {
  asm volatile("global_store_dwordx4 %0, %1, off sc0 sc1" :: "v"(dst), "v"(v) : "memory");
}
__device__ __forceinline__ void st32_cc(void* dst, float v) {
  asm volatile("global_store_dword %0, %1, off sc0 sc1" :: "v"(dst), "v"(v) : "memory");
}
__device__ __forceinline__ void st16_cc(void* dst, unsigned short v) {
  unsigned u = v;
  asm volatile("global_store_short %0, %1, off sc0 sc1" :: "v"(dst), "v"(u) : "memory");
}

// ---------------- setup kernels ----------------

__global__ void k_convert(const float* __restrict__ src, unsigned short* __restrict__ dst, int n) {
  int i = (blockIdx.x * blockDim.x + threadIdx.x) * 4;
  if (i + 3 < n) {
    float4 v = *(const float4*)(src + i);
    dst[i + 0] = f2bf(v.x); dst[i + 1] = f2bf(v.y);
    dst[i + 2] = f2bf(v.z); dst[i + 3] = f2bf(v.w);
  } else {
    for (int j = 0; j < 4 && i + j < n; ++j) dst[i + j] = f2bf(src[i + j]);
  }
}

__global__ void k_wqp(const float* __restrict__ Wcurr, const float* __restrict__ Wprev,
                      unsigned short* __restrict__ dst) {
  int i = blockIdx.x * blockDim.x + threadIdx.x;  // < 128*512
  int row = i >> 9, col = i & 511;
  float v = (row < 64) ? Wcurr[row * 512 + col] : Wprev[(row - 64) * 512 + col];
  dst[i] = f2bf(v);
}

__global__ void k_bias(const float* __restrict__ bih, const float* __restrict__ bhh,
                       float* __restrict__ bsum) {
  int i = blockIdx.x * blockDim.x + threadIdx.x;
  if (i < 4096) bsum[i] = bih[i] + bhh[i];
}

__global__ void k_zero(uint4* __restrict__ p, int n16) {
  int i = blockIdx.x * blockDim.x + threadIdx.x;
  if (i < n16) p[i] = make_uint4(0u, 0u, 0u, 0u);
}

__global__ void k_p0(float* __restrict__ P, const float* __restrict__ bprev) {
  int i = blockIdx.x * blockDim.x + threadIdx.x;  // < 1024*64
  P[i] = bprev[i & 63];
}

// ---------------- persistent kernel ----------------

struct PP {
  const unsigned short *Wih, *Whh, *Wqp;    // bf16 [2][2048][512] x2, [128][512]
  const float *bias;                        // [4096] = [2][4][512]
  unsigned short *X;                        // [2][1024][512] ring
  unsigned short *H0, *H1;                  // [8][1024][512] rings
  const unsigned short *Z;                  // zeros [1024][512]
  const float *bcurr, *bprev, *vv, *Wanc, *banc;
  const float *Wc0, *bc0, *Wc1, *bc1, *Wc2, *bc2;
  float *P;                                 // [12][1024][64]
  float *out;                               // [1024][348]
  unsigned *bar;
};

template <int S>
__device__ __forceinline__ void cls_one(const unsigned short* h, const float* Wc,
                                        const float* bc, float* out, int obase,
                                        int row, int lane) {
  short8 hv = *(const short8*)(h + (size_t)row * HID + lane * 8);
  float hf[8];
#pragma unroll
  for (int j = 0; j < 8; ++j) hf[j] = bf2f((unsigned short)hv[j]);
  float logit[S];
#pragma unroll
  for (int s = 0; s < S; ++s) {
    const float* wr = Wc + s * HID + lane * 8;
    float pd = 0.f;
#pragma unroll
    for (int j = 0; j < 8; ++j) pd += hf[j] * wr[j];
#pragma unroll
    for (int off = 32; off; off >>= 1) pd += __shfl_xor(pd, off);
    logit[s] = pd + bc[s];
  }
  if (lane == 0) {
    float mx = logit[0];
#pragma unroll
    for (int s = 1; s < S; ++s) mx = fmaxf(mx, logit[s]);
    float e[S], den = 0.f;
#pragma unroll
    for (int s = 0; s < S; ++s) { e[s] = __expf(logit[s] - mx); den += e[s]; }
    float inv = 1.f / den;
#pragma unroll
    for (int s = 0; s < S; ++s) st32_cc(out + (size_t)row * OUTW + obase + s, e[s] * inv);
  }
}

// Block roles: b = mt*64 + nt*2 + layer.  layer in {0,1}, nt in [0,32) (16 cells),
// mt in [0,4) (256 rows).  Weights for the block's 64 gate-rows x K=1024 live in
// LDS (128 KB, XOR-swizzled).  C state in registers for all 48 steps.
__global__ void __launch_bounds__(512, 1) k_persist(PP p) {
  extern __shared__ char smem[];
  unsigned short* Wl = (unsigned short*)smem;   // [64][1024] swizzled (128 KB)
  char* Ar = smem + 131072;                     // phase scratch (<= 21504 B)

  const int b = blockIdx.x, tid = threadIdx.x;
  const int wv = tid >> 6, lane = tid & 63;
  const int l16 = lane & 15, kg = lane >> 4;
  const int layer = b & 1;
  const int nt = (b >> 1) & 31;
  const int mt = b >> 6;
  const int wm = wv >> 1, wn = wv & 1;

  // ---- one-time: stage this block's weights into LDS (swizzled) ----
  {
    const unsigned short* Wih = p.Wih + (size_t)layer * NWL;
    const unsigned short* Whh = p.Whh + (size_t)layer * NWL;
#pragma unroll
    for (int i = 0; i < 16; ++i) {
      int G = i * 512 + tid;           // [0, 8192) 16B-chunks
      int gr = G >> 7, q = G & 127;    // gate-row, chunk within row
      int g = gr & 3, cl = gr >> 2;
      int grow = g * 512 + nt * 16 + cl;
      const unsigned short* src = (q < 64) ? (Wih + (size_t)grow * HID + q * 8)
                                           : (Whh + (size_t)grow * HID + (q - 64) * 8);
      short8 v = *(const short8*)src;
      *(short8*)((char*)Wl + gr * 2048 + ((q ^ (gr & 7)) << 4)) = v;
    }
  }
  __syncthreads();

  float creg[2][4][4];
#pragma unroll
  for (int a = 0; a < 2; ++a)
#pragma unroll
    for (int m = 0; m < 4; ++m)
#pragma unroll
      for (int r = 0; r < 4; ++r) creg[a][m][r] = 0.f;

  unsigned ep = 0;
  auto gbar = [&]() {
    asm volatile("s_waitcnt vmcnt(0)" ::: "memory");
    __syncthreads();
    ++ep;
    if (tid == 0) {
      atomicAdd(p.bar, 1u);
      while (__hip_atomic_load(p.bar, __ATOMIC_RELAXED, __HIP_MEMORY_SCOPE_AGENT) < ep * 256u)
        __builtin_amdgcn_s_sleep(8);
    }
    __syncthreads();
  };

  // ---- one layer-step GEMM for this block's slice ----
  auto do_layer = [&](const unsigned short* S0, const unsigned short* S1,
                      unsigned short* Hout, const float* bias) {
    unsigned short* Al = (unsigned short*)Ar;  // [256 rows][40 elems] (80 B rows)
    const int row0 = tid >> 2, kc = tid & 3;

    auto aload = [&](int j, short8& xa, short8& xb) {
      const unsigned short* S = (j < 16) ? S0 : S1;
      const unsigned short* s0 = S + (size_t)(mt * 256 + row0) * HID + (j & 15) * 32 + kc * 8;
      xa = *(const short8*)s0;
      xb = *(const short8*)(s0 + 128 * HID);
    };

    f32x4 acc[2][4];
#pragma unroll
    for (int t = 0; t < 2; ++t)
#pragma unroll
      for (int m = 0; m < 4; ++m) acc[t][m] = (f32x4)(0.f);

    short8 ra0, rb0, ra1, rb1, ra2, rb2;
    aload(0, ra0, rb0);
    aload(1, ra1, rb1);
    aload(2, ra2, rb2);

    auto tile = [&](int j, short8& xa, short8& xb) {
      asm volatile("s_waitcnt lgkmcnt(0)" ::: "memory");
      __builtin_amdgcn_s_barrier();                 // all waves done reading prev tile
      *(short8*)((char*)Al + row0 * 80 + kc * 16) = xa;
      *(short8*)((char*)Al + (row0 + 128) * 80 + kc * 16) = xb;
      if (j + 3 < 32) aload(j + 3, xa, xb);         // refill ring slot (3 ahead)
      asm volatile("s_waitcnt lgkmcnt(0)" ::: "memory");
      __builtin_amdgcn_s_barrier();                 // tile j visible
      __builtin_amdgcn_sched_barrier(0);
      short8 af[4];
#pragma unroll
      for (int m = 0; m < 4; ++m) {
        const int arow = wm * 64 + m * 16 + l16;
        af[m] = *(const short8*)((char*)Al + arow * 80 + kg * 16);
      }
#pragma unroll
      for (int t = 0; t < 2; ++t) {
        const int gr = wn * 32 + t * 16 + l16;
        const int q = j * 4 + kg;
        short8 bf = *(const short8*)((char*)Wl + gr * 2048 + ((q ^ (gr & 7)) << 4));
#pragma unroll
        for (int m = 0; m < 4; ++m) acc[t][m] = mfma_bf16(af[m], bf, acc[t][m]);
      }
    };

    for (int j = 0; j < 30; j += 3) {
      tile(j, ra0, rb0);
      tile(j + 1, ra1, rb1);
      tile(j + 2, ra2, rb2);
    }
    tile(30, ra0, rb0);
    tile(31, ra1, rb1);

    // epilogue: bias, 4-lane gate gather, cell update (C in regs), h -> LDS -> global
    const int g = l16 & 3, cl4 = l16 >> 2;
    asm volatile("s_waitcnt lgkmcnt(0)" ::: "memory");
    __builtin_amdgcn_s_barrier();                   // done with tile 31 A-data
#pragma unroll
    for (int t = 0; t < 2; ++t) {
      const int lc = wn * 8 + t * 4 + cl4;          // local cell [0,16)
      const float bs = bias[g * HID + nt * 16 + lc];
#pragma unroll
      for (int m = 0; m < 4; ++m)
#pragma unroll
        for (int r = 0; r < 4; ++r) {
          float val = acc[t][m][r] + bs;
          float gf = __shfl(val, (lane & ~3) + 1);
          float gg = __shfl(val, (lane & ~3) + 2);
          float go = __shfl(val, (lane & ~3) + 3);
          if (g == 0) {
            float cn = sigm(gf) * creg[t][m][r] + sigm(val) * tanhf(gg);
            float hn = sigm(go) * tanhf(cn);
            creg[t][m][r] = cn;
            const int lr = wm * 64 + m * 16 + kg * 4 + r;
            *(unsigned short*)((char*)Al + lr * 32 + lc * 2) = f2bf(hn);
          }
        }
    }
    asm volatile("s_waitcnt lgkmcnt(0)" ::: "memory");
    __builtin_amdgcn_s_barrier();
    {
      const int lr = tid >> 1, half = tid & 1;
      short8 v = *(const short8*)((char*)Al + lr * 32 + half * 16);
      st128_cc(Hout + (size_t)(mt * 256 + lr) * HID + nt * 16 + half * 8, v);
    }
  };

  auto do_cls = [&](int c) {
    const int t0 = 4 * c;
    const int row = (b >> 1) * 8 + wv;    // L0 blocks only: b>>1 in [0,128)
    const unsigned short* hA = p.H1 + (size_t)(t0 % 8) * NBH;
    const unsigned short* hB = p.H1 + (size_t)((t0 + 1) % 8) * NBH;
    const unsigned short* hC = p.H1 + (size_t)((t0 + 2) % 8) * NBH;
    const int base = c * 29;
    cls_one<8>(hA, p.Wc0, p.bc0, p.out, base, row, lane);
    cls_one<6>(hB, p.Wc1, p.bc1, p.out, base + 8, row, lane);
    cls_one<4>(hC, p.Wc2, p.bc2, p.out, base + 14, row, lane);
  };

  auto do_anchor = [&](int c) {
    if ((b & 3) == 0) {
      const int t3 = 4 * c + 3;
      const unsigned short* h1 = p.H1 + (size_t)(t3 % 8) * NBH;
      const int rb = (b >> 2) * 16;
      unsigned short* A16 = (unsigned short*)Ar;        // [16][520] (1040 B rows)
      float* Qs = (float*)(Ar + 16640);                 // [16][64]
      float* ss = (float*)(Ar + 16640 + 4096);          // [16][12]
#pragma unroll
      for (int i = 0; i < 2; ++i) {
        int G = i * 512 + tid;
        int row = G >> 6, q = G & 63;
        short8 v = *(const short8*)(h1 + (size_t)(rb + row) * HID + q * 8);
        *(short8*)((char*)A16 + row * 1040 + q * 16) = v;
      }
      __syncthreads();
      f32x4 aq = (f32x4)(0.f);
#pragma unroll
      for (int kt = 0; kt < 16; ++kt) {
        short8 af = *(const short8*)((char*)A16 + l16 * 1040 + kt * 64 + kg * 16);
        short8 bf = *(const short8*)(p.Wqp + (size_t)(wv * 16 + l16) * HID + kt * 32 + kg * 8);
        aq = mfma_bf16(af, bf, aq);
      }
      const int co = wv * 16 + l16;
#pragma unroll
      for (int r = 0; r < 4; ++r) {
        const int lr = kg * 4 + r;
        if (co < 64) {
          Qs[lr * 64 + co] = aq[r] + p.bcurr[co];
        } else if (c + 1 < 12) {
          st32_cc(p.P + (size_t)(c + 1) * (BATCH * 64) + (size_t)(rb + lr) * 64 + (co - 64),
                  aq[r] + p.bprev[co - 64]);
        }
      }
      __syncthreads();
#pragma unroll
      for (int rr = 0; rr < 2; ++rr) {
        const int lr = wv * 2 + rr;
        const float q = Qs[lr * 64 + lane];
        const float vl = p.vv[lane];
        float pv[11];
#pragma unroll
        for (int k = 0; k < 11; ++k)
          pv[k] = (k < c) ? p.P[(size_t)k * (BATCH * 64) + (size_t)(rb + lr) * 64 + lane] : 0.f;
#pragma unroll
        for (int k = 0; k < 11; ++k) {
          if (k < c) {
            float tt = tanhf(pv[k] + q) * vl;
#pragma unroll
            for (int off = 32; off; off >>= 1) tt += __shfl_xor(tt, off);
            if (lane == 0) ss[lr * 12 + k] = sigm(tt);
          }
        }
      }
      __syncthreads();
#pragma unroll
      for (int rr = 0; rr < 2; ++rr) {
        const int lr = wv * 2 + rr;
        if (lane < 11) {
          float ov = (lane < c) ? ss[lr * 12 + lane] : 0.f;
          st32_cc(p.out + (size_t)(rb + lr) * OUTW + c * 29 + 18 + lane, ov);
        }
      }
      {
        unsigned short* Xn = p.X + (size_t)((c + 1) & 1) * NBH;
        const int d = tid;
        float wk[11];
#pragma unroll
        for (int k = 0; k < 11; ++k) wk[k] = (k < c) ? p.Wanc[d * 11 + k] : 0.f;
        const float bd = p.banc[d];
        for (int lr = 0; lr < 16; ++lr) {
          float x = bd;
#pragma unroll
          for (int k = 0; k < 11; ++k)
            if (k < c) x += ss[lr * 12 + k] * wk[k];
          st16_cc(Xn + (size_t)(rb + lr) * HID + d, f2bf(x));
        }
      }
    }
    __threadfence();   // per-cycle L1/L2 invalidate (ring-staleness guarantee)
  };

  auto H0p = [&](int t) -> unsigned short* { return p.H0 + (size_t)(t % 8) * NBH; };
  auto H1p = [&](int t) -> unsigned short* { return p.H1 + (size_t)(t % 8) * NBH; };
  auto Xp  = [&](int c) -> const unsigned short* { return p.X + (size_t)(c & 1) * NBH; };
  const float* bias0 = p.bias;
  const float* bias1 = p.bias + 2048;

  // phase 0: L0(step 0)
  if (layer == 0) do_layer(Xp(0), p.Z, H0p(0), bias0);
  gbar();

  for (int c = 0; c < 12; ++c) {
    const int t0 = 4 * c;
    for (int k = 0; k < 3; ++k) {            // phases 1-3: L1(t) || L0(t+1)
      const int t = t0 + k;
      if (layer == 1) do_layer(H0p(t), (t == 0) ? p.Z : H1p(t - 1), H1p(t), bias1);
      else            do_layer(Xp(c), H0p(t), H0p(t + 1), bias0);
      gbar();
    }
    // phase 4: L1(t3) || cls x3
    if (layer == 1) do_layer(H0p(t0 + 3), H1p(t0 + 2), H1p(t0 + 3), bias1);
    else            do_cls(c);
    gbar();
    // phase 5: anchor (qp + scores + X embed) on 64 blocks
    do_anchor(c);
    gbar();
    // phase 6: L0(t0+4) with new X
    if (c < 11) {
      if (layer == 0) do_layer(Xp(c + 1), H0p(t0 + 3), H0p(t0 + 4), bias0);
      gbar();
    }
  }
}

// ---------------- launcher ----------------

extern "C" void kernel_launch(void* const* d_in, const int* in_sizes, int n_in,
                              void* d_out, int out_size, void* d_ws, size_t ws_size,
                              hipStream_t stream) {
  const float* x0    = (const float*)d_in[0];
  const float* lWih  = (const float*)d_in[1];
  const float* lWhh  = (const float*)d_in[2];
  const float* lbih  = (const float*)d_in[3];
  const float* lbhh  = (const float*)d_in[4];
  const float* Wc0   = (const float*)d_in[5];
  const float* bc0   = (const float*)d_in[6];
  const float* Wc1   = (const float*)d_in[7];
  const float* bc1   = (const float*)d_in[8];
  const float* Wc2   = (const float*)d_in[9];
  const float* bc2   = (const float*)d_in[10];
  const float* Wprev = (const float*)d_in[11];
  const float* bprev = (const float*)d_in[12];
  const float* Wcurr = (const float*)d_in[13];
  const float* bcurr = (const float*)d_in[14];
  const float* Wanc  = (const float*)d_in[15];
  const float* banc  = (const float*)d_in[16];
  const float* v     = (const float*)d_in[17];
  float* out = (float*)d_out;

  const size_t NW = 2 * (size_t)NWL;

  char* ws = (char*)d_ws;
  size_t off = 0;
  auto alloc = [&](size_t bytes) { char* q = ws + off; off += (bytes + 255) & ~(size_t)255; return q; };
  unsigned short* Wih_b = (unsigned short*)alloc(NW * 2);
  unsigned short* Whh_b = (unsigned short*)alloc(NW * 2);
  unsigned short* Wqp_b = (unsigned short*)alloc(128 * 512 * 2);
  float*          biasS = (float*)alloc(4096 * 4);
  unsigned short* Xb    = (unsigned short*)alloc(2 * (size_t)NBH * 2);
  unsigned short* H0b   = (unsigned short*)alloc(8 * (size_t)NBH * 2);
  unsigned short* H1b   = (unsigned short*)alloc(8 * (size_t)NBH * 2);
  unsigned short* Zb    = (unsigned short*)alloc((size_t)NBH * 2);
  unsigned*       bar   = (unsigned*)alloc(256);
  float*          P     = (float*)alloc((size_t)12 * BATCH * 64 * 4);

  k_convert<<<dim3((NW / 4 + 255) / 256), dim3(256), 0, stream>>>(lWih, Wih_b, (int)NW);
  k_convert<<<dim3((NW / 4 + 255) / 256), dim3(256), 0, stream>>>(lWhh, Whh_b, (int)NW);
  k_convert<<<dim3((NBH / 4 + 255) / 256), dim3(256), 0, stream>>>(x0, Xb, (int)NBH);
  k_wqp<<<dim3(256), dim3(256), 0, stream>>>(Wcurr, Wprev, Wqp_b);
  k_bias<<<dim3(16), dim3(256), 0, stream>>>(lbih, lbhh, biasS);
  {
    // zero Z + bar (contiguous 256B-aligned allocs)
    size_t zb = (size_t)NBH * 2 + 256;
    int n16 = (int)(zb / 16);
    k_zero<<<dim3((n16 + 255) / 256), dim3(256), 0, stream>>>((uint4*)Zb, n16);
  }
  k_p0<<<dim3(256), dim3(256), 0, stream>>>(P, bprev);

  PP pp;
  pp.Wih = Wih_b; pp.Whh = Whh_b; pp.Wqp = Wqp_b; pp.bias = biasS;
  pp.X = Xb; pp.H0 = H0b; pp.H1 = H1b; pp.Z = Zb;
  pp.bcurr = bcurr; pp.bprev = bprev; pp.vv = v; pp.Wanc = Wanc; pp.banc = banc;
  pp.Wc0 = Wc0; pp.bc0 = bc0; pp.Wc1 = Wc1; pp.bc1 = bc1; pp.Wc2 = Wc2; pp.bc2 = bc2;
  pp.P = P; pp.out = out; pp.bar = bar;

  (void)hipFuncSetAttribute((const void*)k_persist,
                            hipFuncAttributeMaxDynamicSharedMemorySize, 152576);
  void* args[] = {&pp};
  (void)hipLaunchCooperativeKernel((const void*)k_persist, dim3(256), dim3(512),
                                   args, 152576, stream);

  (void)in_sizes; (void)n_in; (void)out_size; (void)ws_size;
}